// Round 1
// baseline (2126.262 us; speedup 1.0000x reference)
//
#include <hip/hip_runtime.h>
#include <math.h>

// Problem constants
constexpr int B  = 2;
constexpr int C  = 64;
constexpr int H  = 128;
constexpr int W  = 128;
constexpr int O  = 64;
constexpr int DG = 8;
constexpr int K  = 3;
constexpr int KK = K * K;           // 9
constexpr int HW = H * W;           // 16384
constexpr int CG = C / DG;          // 8 channels per deform group
constexpr int OM_C  = 3 * DG * KK;  // 216
constexpr int OFF_C = 2 * DG * KK;  // 144
constexpr int MSK_C = DG * KK;      // 72
constexpr float MRM = 10.0f;

// ---------------- Kernel 1: conv_offset_mask + transform ----------------
// Each thread computes OCPT1 consecutive output channels of the 3x3 conv for
// one pixel, then applies tanh/sigmoid fusion and writes offset / mask.
constexpr int OCPT1 = 8;
constexpr int NQ1   = OM_C / OCPT1;  // 27

__global__ void __launch_bounds__(256)
conv_offset_mask_kernel(const float* __restrict__ x1,
                        const float* __restrict__ w_om,
                        const float* __restrict__ b_om,
                        const float* __restrict__ pre_offset,
                        const float* __restrict__ pre_sim,
                        float* __restrict__ offset,
                        float* __restrict__ mask) {
    int idx = blockIdx.x * blockDim.x + threadIdx.x;
    // idx = ((b*NQ1 + q)*H + h)*W + w  -> w contiguous within wave, q uniform
    int w  = idx & (W - 1);
    int h  = (idx >> 7) & (H - 1);
    int bq = idx >> 14;            // b*NQ1 + q
    int q  = bq % NQ1;
    int b  = bq / NQ1;
    int oc0 = q * OCPT1;

    float acc[OCPT1];
#pragma unroll
    for (int j = 0; j < OCPT1; ++j) acc[j] = 0.0f;

    const float* xb = x1 + b * C * HW;

    for (int t = 0; t < KK; ++t) {
        int ky = t / 3, kx = t % 3;
        int row = h + ky - 1;
        int col = w + kx - 1;
        bool inb = (row >= 0) && (row < H) && (col >= 0) && (col < W);
        int rp = (inb ? row : 0) * W + (inb ? col : 0);
        float scale = inb ? 1.0f : 0.0f;
        const float* wp = w_om + oc0 * (C * KK) + t;  // + ic*KK later
        for (int ic = 0; ic < C; ++ic) {
            float xv = xb[ic * HW + rp] * scale;
#pragma unroll
            for (int j = 0; j < OCPT1; ++j)
                acc[j] += xv * wp[j * (C * KK) + ic * KK];
        }
    }

    int p = h * W + w;
#pragma unroll
    for (int j = 0; j < OCPT1; ++j) {
        int oc = oc0 + j;
        float v = acc[j] + b_om[oc];
        if (oc < OFF_C) {
            offset[(b * OFF_C + oc) * HW + p] =
                MRM * tanhf(v) + pre_offset[(b * OFF_C + oc) * HW + p];
        } else {
            int jm = oc - OFF_C;
            float s = pre_sim[(b * MSK_C + jm) * HW + p];
            mask[(b * MSK_C + jm) * HW + p] = 1.0f / (1.0f + expf(-v * s));
        }
    }
}

// ---------------- Kernel 2: modulated deformable conv ----------------
// Each thread computes OCPT2 output channels for one pixel. Bilinear sampling
// is shared across the CG channels of each deform group; weights are read via
// wave-uniform scalar loads.
constexpr int OCPT2 = 16;
constexpr int NQ2   = O / OCPT2;  // 4

__global__ void __launch_bounds__(256)
deform_conv_kernel(const float* __restrict__ x0,
                   const float* __restrict__ offset,
                   const float* __restrict__ mask,
                   const float* __restrict__ weight,
                   const float* __restrict__ bias,
                   float* __restrict__ out) {
    int idx = blockIdx.x * blockDim.x + threadIdx.x;
    int w  = idx & (W - 1);
    int h  = (idx >> 7) & (H - 1);
    int bq = idx >> 14;        // b*NQ2 + q
    int q  = bq & (NQ2 - 1);
    int b  = bq >> 2;
    int oc0 = q * OCPT2;
    int p = h * W + w;

    float acc[OCPT2];
#pragma unroll
    for (int o = 0; o < OCPT2; ++o) acc[o] = bias[oc0 + o];

    const float* offb = offset + b * OFF_C * HW + p;
    const float* mb   = mask + b * MSK_C * HW + p;
    const float* xb   = x0 + b * C * HW;

    for (int g = 0; g < DG; ++g) {
        const float* xg = xb + g * CG * HW;
#pragma unroll
        for (int i = 0; i < KK; ++i) {
            int gi = g * KK + i;
            float offy = offb[(2 * gi) * HW];
            float offx = offb[(2 * gi + 1) * HW];
            float m    = mb[gi * HW];

            float py = offy + (float)(h - 1 + i / 3);
            float px = offx + (float)(w - 1 + i % 3);
            float fy = floorf(py), fx = floorf(px);
            float ly = py - fy, lx = px - fx;
            float hy = 1.0f - ly, hx = 1.0f - lx;
            int y0 = (int)fy, x0i = (int)fx;
            int y1 = y0 + 1, x1i = x0i + 1;
            bool vy0 = (y0 >= 0) && (y0 < H);
            bool vy1 = (y1 >= 0) && (y1 < H);
            bool vx0 = (x0i >= 0) && (x0i < W);
            bool vx1 = (x1i >= 0) && (x1i < W);
            int cy0 = min(max(y0, 0), H - 1), cy1 = min(max(y1, 0), H - 1);
            int cx0 = min(max(x0i, 0), W - 1), cx1 = min(max(x1i, 0), W - 1);
            float w00 = hy * hx * ((vy0 && vx0) ? 1.0f : 0.0f) * m;
            float w01 = hy * lx * ((vy0 && vx1) ? 1.0f : 0.0f) * m;
            float w10 = ly * hx * ((vy1 && vx0) ? 1.0f : 0.0f) * m;
            float w11 = ly * lx * ((vy1 && vx1) ? 1.0f : 0.0f) * m;
            int i00 = cy0 * W + cx0, i01 = cy0 * W + cx1;
            int i10 = cy1 * W + cx0, i11 = cy1 * W + cx1;

            const float* wp = weight + oc0 * (C * KK) + (g * CG) * KK + i;
#pragma unroll
            for (int c = 0; c < CG; ++c) {
                const float* xc = xg + c * HW;
                float v = w00 * xc[i00] + w01 * xc[i01] +
                          w10 * xc[i10] + w11 * xc[i11];
#pragma unroll
                for (int o = 0; o < OCPT2; ++o)
                    acc[o] += v * wp[o * (C * KK) + c * KK];
            }
        }
    }

    float* ob = out + (b * O) * HW + p;
#pragma unroll
    for (int o = 0; o < OCPT2; ++o) ob[(oc0 + o) * HW] = acc[o];
}

// ---------------- Launch ----------------
extern "C" void kernel_launch(void* const* d_in, const int* in_sizes, int n_in,
                              void* d_out, int out_size, void* d_ws, size_t ws_size,
                              hipStream_t stream) {
    (void)in_sizes; (void)n_in; (void)out_size; (void)ws_size;
    const float* x0         = (const float*)d_in[0];
    const float* x1         = (const float*)d_in[1];
    const float* pre_offset = (const float*)d_in[2];
    const float* pre_sim    = (const float*)d_in[3];
    const float* weight     = (const float*)d_in[4];
    const float* bias       = (const float*)d_in[5];
    const float* w_om       = (const float*)d_in[6];
    const float* b_om       = (const float*)d_in[7];
    float* out = (float*)d_out;

    // workspace: offset (B*144*HW) then mask (B*72*HW), fp32
    float* offset = (float*)d_ws;
    float* mask   = offset + (size_t)B * OFF_C * HW;

    {
        int total = B * NQ1 * H * W;     // 884736
        int block = 256;
        int grid = total / block;
        conv_offset_mask_kernel<<<grid, block, 0, stream>>>(
            x1, w_om, b_om, pre_offset, pre_sim, offset, mask);
    }
    {
        int total = B * NQ2 * H * W;     // 131072
        int block = 256;
        int grid = total / block;
        deform_conv_kernel<<<grid, block, 0, stream>>>(
            x0, offset, mask, weight, bias, out);
    }
}

// Round 2
// 373.387 us; speedup vs baseline: 5.6945x; 5.6945x over previous
//
#include <hip/hip_runtime.h>
#include <math.h>

// Problem constants
constexpr int B  = 2;
constexpr int C  = 64;
constexpr int H  = 128;
constexpr int W  = 128;
constexpr int O  = 64;
constexpr int DG = 8;
constexpr int K  = 3;
constexpr int KK = K * K;           // 9
constexpr int HW = H * W;           // 16384
constexpr int CG = C / DG;          // 8
constexpr int OM_C  = 3 * DG * KK;  // 216
constexpr int OFF_C = 2 * DG * KK;  // 144
constexpr int MSK_C = DG * KK;      // 72
constexpr float MRM = 10.0f;

// ---------------- Kernel 0: weight transposes ----------------
// wT[(g*KK+i)*CG + c][o]  = weight[o][(g*CG+c)*KK + i]   (576 x 64)
// w_omT[(ic*KK+t)][oc]    = w_om[oc][ic*KK + t]          (576 x 216)
constexpr int WT_N   = 576 * 64;    // 36864
constexpr int WOMT_N = 576 * 216;   // 124416

__global__ void __launch_bounds__(256)
prep_weights_kernel(const float* __restrict__ weight,
                    const float* __restrict__ w_om,
                    float* __restrict__ wT,
                    float* __restrict__ w_omT) {
    int idx = blockIdx.x * 256 + threadIdx.x;
    if (idx < WT_N) {
        int r = idx / O;        // (g*KK+i)*CG + c
        int o = idx - r * O;
        int g = r / (KK * CG);
        int rem = r - g * (KK * CG);
        int i = rem / CG;
        int c = rem - i * CG;
        int kidx = (g * CG + c) * KK + i;
        wT[idx] = weight[o * (C * KK) + kidx];
    }
    int idx2 = idx - WT_N;
    if (idx2 >= 0 && idx2 < WOMT_N) {
        int r = idx2 / OM_C;    // ic*KK + t
        int oc = idx2 - r * OM_C;
        w_omT[idx2] = w_om[oc * (C * KK) + r];
    }
}

// ---------------- Kernel 1: conv_offset_mask + transform ----------------
// grid = (HW/256, 9, B); q = blockIdx.y is wave-uniform by construction, so
// all weight addresses are provably uniform -> scalar (s_load) weight reads.
constexpr int OCPT1 = 24;   // 216 = 9 * 24; q<6 -> offset chans, q>=6 -> mask

__global__ void __launch_bounds__(256)
conv_offset_mask_kernel(const float* __restrict__ x1,
                        const float* __restrict__ w_omT,
                        const float* __restrict__ b_om,
                        const float* __restrict__ pre_offset,
                        const float* __restrict__ pre_sim,
                        float* __restrict__ offset,
                        float* __restrict__ mask) {
    int p = blockIdx.x * 256 + threadIdx.x;   // pixel
    int q = blockIdx.y;                        // channel group (uniform)
    int b = blockIdx.z;
    int h = p >> 7;
    int w = p & (W - 1);
    int oc0 = q * OCPT1;

    float acc[OCPT1];
#pragma unroll
    for (int j = 0; j < OCPT1; ++j) acc[j] = 0.0f;

    // border handling: clamped index + validity scale
    int   rofs[3];
    float rval[3];
    int   cofs[3];
    float cval[3];
#pragma unroll
    for (int t = 0; t < 3; ++t) {
        int row = h + t - 1;
        bool vr = (row >= 0) && (row < H);
        rofs[t] = (vr ? row : 0) * W;
        rval[t] = vr ? 1.0f : 0.0f;
        int col = w + t - 1;
        bool vc = (col >= 0) && (col < W);
        cofs[t] = vc ? col : 0;
        cval[t] = vc ? 1.0f : 0.0f;
    }

    const float* xb = x1 + b * C * HW;

    for (int ic = 0; ic < C; ++ic) {
        const float* xc = xb + ic * HW;
        float xv[KK];
#pragma unroll
        for (int ky = 0; ky < 3; ++ky)
#pragma unroll
            for (int kx = 0; kx < 3; ++kx)
                xv[ky * 3 + kx] = xc[rofs[ky] + cofs[kx]] * (rval[ky] * cval[kx]);

        const float* wrow = w_omT + ic * KK * OM_C + oc0;  // uniform address
#pragma unroll
        for (int t = 0; t < KK; ++t) {
#pragma unroll
            for (int j = 0; j < OCPT1; ++j)
                acc[j] = fmaf(xv[t], wrow[t * OM_C + j], acc[j]);
        }
    }

    if (q < 6) {  // offset channels
#pragma unroll
        for (int j = 0; j < OCPT1; ++j) {
            int oc = oc0 + j;
            float v = acc[j] + b_om[oc];
            size_t o_idx = (size_t)(b * OFF_C + oc) * HW + p;
            offset[o_idx] = MRM * tanhf(v) + pre_offset[o_idx];
        }
    } else {      // mask channels
#pragma unroll
        for (int j = 0; j < OCPT1; ++j) {
            int jm = oc0 - OFF_C + j;
            float v = acc[j] + b_om[oc0 + j];
            size_t m_idx = (size_t)(b * MSK_C + jm) * HW + p;
            float s = pre_sim[m_idx];
            mask[m_idx] = 1.0f / (1.0f + expf(-v * s));
        }
    }
}

// ---------------- Kernel 2: modulated deformable conv ----------------
// grid = (HW/256, 4, B); oc-quarter q uniform -> scalar weight loads from wT.
constexpr int OCPT2 = 16;

__global__ void __launch_bounds__(256)
deform_conv_kernel(const float* __restrict__ x0,
                   const float* __restrict__ offset,
                   const float* __restrict__ mask,
                   const float* __restrict__ wT,
                   const float* __restrict__ bias,
                   float* __restrict__ out) {
    int p = blockIdx.x * 256 + threadIdx.x;
    int q = blockIdx.y;
    int b = blockIdx.z;
    int h = p >> 7;
    int w = p & (W - 1);
    int oc0 = q * OCPT2;

    float acc[OCPT2];
#pragma unroll
    for (int o = 0; o < OCPT2; ++o) acc[o] = bias[oc0 + o];

    const float* offb = offset + (size_t)b * OFF_C * HW + p;
    const float* mb   = mask + (size_t)b * MSK_C * HW + p;
    const float* xb   = x0 + (size_t)b * C * HW;

    for (int g = 0; g < DG; ++g) {
        const float* xg = xb + g * CG * HW;
#pragma unroll
        for (int i = 0; i < KK; ++i) {
            int gi = g * KK + i;
            float offy = offb[(size_t)(2 * gi) * HW];
            float offx = offb[(size_t)(2 * gi + 1) * HW];
            float m    = mb[(size_t)gi * HW];

            float py = offy + (float)(h - 1 + i / 3);
            float px = offx + (float)(w - 1 + i % 3);
            float fy = floorf(py), fx = floorf(px);
            float ly = py - fy, lx = px - fx;
            float hy = 1.0f - ly, hx = 1.0f - lx;
            int y0 = (int)fy, x0i = (int)fx;
            int y1 = y0 + 1, x1i = x0i + 1;
            bool vy0 = (y0 >= 0) && (y0 < H);
            bool vy1 = (y1 >= 0) && (y1 < H);
            bool vx0 = (x0i >= 0) && (x0i < W);
            bool vx1 = (x1i >= 0) && (x1i < W);
            int cy0 = min(max(y0, 0), H - 1), cy1 = min(max(y1, 0), H - 1);
            int cx0 = min(max(x0i, 0), W - 1), cx1 = min(max(x1i, 0), W - 1);
            float w00 = hy * hx * ((vy0 && vx0) ? 1.0f : 0.0f) * m;
            float w01 = hy * lx * ((vy0 && vx1) ? 1.0f : 0.0f) * m;
            float w10 = ly * hx * ((vy1 && vx0) ? 1.0f : 0.0f) * m;
            float w11 = ly * lx * ((vy1 && vx1) ? 1.0f : 0.0f) * m;
            int i00 = cy0 * W + cx0, i01 = cy0 * W + cx1;
            int i10 = cy1 * W + cx0, i11 = cy1 * W + cx1;

            const float* wrow = wT + (size_t)(gi * CG) * O + oc0;  // uniform
#pragma unroll
            for (int c = 0; c < CG; ++c) {
                const float* xc = xg + c * HW;
                float v = w00 * xc[i00] + w01 * xc[i01] +
                          w10 * xc[i10] + w11 * xc[i11];
#pragma unroll
                for (int o = 0; o < OCPT2; ++o)
                    acc[o] = fmaf(v, wrow[c * O + o], acc[o]);
            }
        }
    }

    float* ob = out + ((size_t)b * O + oc0) * HW + p;
#pragma unroll
    for (int o = 0; o < OCPT2; ++o) ob[(size_t)o * HW] = acc[o];
}

// ---------------- Launch ----------------
extern "C" void kernel_launch(void* const* d_in, const int* in_sizes, int n_in,
                              void* d_out, int out_size, void* d_ws, size_t ws_size,
                              hipStream_t stream) {
    (void)in_sizes; (void)n_in; (void)out_size; (void)ws_size;
    const float* x0         = (const float*)d_in[0];
    const float* x1         = (const float*)d_in[1];
    const float* pre_offset = (const float*)d_in[2];
    const float* pre_sim    = (const float*)d_in[3];
    const float* weight     = (const float*)d_in[4];
    const float* bias       = (const float*)d_in[5];
    const float* w_om       = (const float*)d_in[6];
    const float* b_om       = (const float*)d_in[7];
    float* out = (float*)d_out;

    // ws layout (floats):
    float* offset = (float*)d_ws;                       // B*144*HW
    float* mask   = offset + (size_t)B * OFF_C * HW;    // B*72*HW
    float* wT     = mask + (size_t)B * MSK_C * HW;      // 576*64
    float* w_omT  = wT + WT_N;                          // 576*216

    {
        int total = WT_N + WOMT_N;   // 161280
        prep_weights_kernel<<<(total + 255) / 256, 256, 0, stream>>>(
            weight, w_om, wT, w_omT);
    }
    {
        dim3 grid(HW / 256, OM_C / OCPT1, B);   // (64, 9, 2)
        conv_offset_mask_kernel<<<grid, 256, 0, stream>>>(
            x1, w_omT, b_om, pre_offset, pre_sim, offset, mask);
    }
    {
        dim3 grid(HW / 256, O / OCPT2, B);      // (64, 4, 2)
        deform_conv_kernel<<<grid, 256, 0, stream>>>(
            x0, offset, mask, wT, bias, out);
    }
}

// Round 3
// 176.911 us; speedup vs baseline: 12.0188x; 2.1106x over previous
//
#include <hip/hip_runtime.h>
#include <math.h>

// Problem constants
constexpr int B  = 2;
constexpr int C  = 64;
constexpr int H  = 128;
constexpr int W  = 128;
constexpr int O  = 64;
constexpr int DG = 8;
constexpr int K  = 3;
constexpr int KK = K * K;           // 9
constexpr int HW = H * W;           // 16384
constexpr int CG = C / DG;          // 8
constexpr int OM_C  = 3 * DG * KK;  // 216
constexpr int OFF_C = 2 * DG * KK;  // 144
constexpr int MSK_C = DG * KK;      // 72
constexpr float MRM = 10.0f;

// ---------------- Kernel 0: weight transposes + x0 channel-interleave ----
// wT[(g*KK+i)*CG + c][o]  = weight[o][(g*CG+c)*KK + i]   (576 x 64)
// w_omT[(ic*KK+t)][oc]    = w_om[oc][ic*KK + t]          (576 x 216)
// x0T[((b*DG+g)*HW + p)*CG + c] = x0[b][g*CG+c][p]       (channel-interleaved)
constexpr int WT_N   = 576 * 64;     // 36864
constexpr int WOMT_N = 576 * 216;    // 124416
constexpr int X0T_N  = B * C * HW;   // 2097152

__global__ void __launch_bounds__(256)
prep_kernel(const float* __restrict__ weight,
            const float* __restrict__ w_om,
            const float* __restrict__ x0,
            float* __restrict__ wT,
            float* __restrict__ w_omT,
            float* __restrict__ x0T) {
    int idx = blockIdx.x * 256 + threadIdx.x;
    if (idx < X0T_N) {
        int p  = idx & (HW - 1);
        int ch = (idx >> 14) & (C - 1);
        int b  = idx >> 20;
        x0T[((size_t)((b * DG + (ch >> 3)) * HW + p) << 3) + (ch & 7)] = x0[idx];
    }
    int i1 = idx - X0T_N;
    if (i1 >= 0 && i1 < WT_N) {
        int r = i1 / O;          // (g*KK+i)*CG + c
        int o = i1 - r * O;
        int g = r / (KK * CG);
        int rem = r - g * (KK * CG);
        int i = rem / CG;
        int c = rem - i * CG;
        wT[i1] = weight[o * (C * KK) + (g * CG + c) * KK + i];
    }
    int i2 = i1 - WT_N;
    if (i2 >= 0 && i2 < WOMT_N) {
        int r = i2 / OM_C;       // ic*KK + t
        int oc = i2 - r * OM_C;
        w_omT[i2] = w_om[oc * (C * KK) + r];
    }
}

// ---------------- Kernel 1: conv_offset_mask + transform ----------------
constexpr int OCPT1 = 24;   // 216 = 9 * 24; q<6 -> offset chans, q>=6 -> mask

__global__ void __launch_bounds__(256)
conv_offset_mask_kernel(const float* __restrict__ x1,
                        const float* __restrict__ w_omT,
                        const float* __restrict__ b_om,
                        const float* __restrict__ pre_offset,
                        const float* __restrict__ pre_sim,
                        float* __restrict__ offset,
                        float* __restrict__ mask) {
    int p = blockIdx.x * 256 + threadIdx.x;   // pixel
    int q = blockIdx.y;                        // channel group (uniform)
    int b = blockIdx.z;
    int h = p >> 7;
    int w = p & (W - 1);
    int oc0 = q * OCPT1;

    float acc[OCPT1];
#pragma unroll
    for (int j = 0; j < OCPT1; ++j) acc[j] = 0.0f;

    int   rofs[3];
    float rval[3];
    int   cofs[3];
    float cval[3];
#pragma unroll
    for (int t = 0; t < 3; ++t) {
        int row = h + t - 1;
        bool vr = (row >= 0) && (row < H);
        rofs[t] = (vr ? row : 0) * W;
        rval[t] = vr ? 1.0f : 0.0f;
        int col = w + t - 1;
        bool vc = (col >= 0) && (col < W);
        cofs[t] = vc ? col : 0;
        cval[t] = vc ? 1.0f : 0.0f;
    }

    const float* xb = x1 + b * C * HW;

    for (int ic = 0; ic < C; ++ic) {
        const float* xc = xb + ic * HW;
        float xv[KK];
#pragma unroll
        for (int ky = 0; ky < 3; ++ky)
#pragma unroll
            for (int kx = 0; kx < 3; ++kx)
                xv[ky * 3 + kx] = xc[rofs[ky] + cofs[kx]] * (rval[ky] * cval[kx]);

        const float* wrow = w_omT + ic * KK * OM_C + oc0;  // uniform address
#pragma unroll
        for (int t = 0; t < KK; ++t) {
#pragma unroll
            for (int j = 0; j < OCPT1; ++j)
                acc[j] = fmaf(xv[t], wrow[t * OM_C + j], acc[j]);
        }
    }

    if (q < 6) {  // offset channels
#pragma unroll
        for (int j = 0; j < OCPT1; ++j) {
            int oc = oc0 + j;
            float v = acc[j] + b_om[oc];
            size_t o_idx = (size_t)(b * OFF_C + oc) * HW + p;
            offset[o_idx] = MRM * tanhf(v) + pre_offset[o_idx];
        }
    } else {      // mask channels
#pragma unroll
        for (int j = 0; j < OCPT1; ++j) {
            int jm = oc0 - OFF_C + j;
            float v = acc[j] + b_om[oc0 + j];
            size_t m_idx = (size_t)(b * MSK_C + jm) * HW + p;
            float s = pre_sim[m_idx];
            mask[m_idx] = 1.0f / (1.0f + expf(-v * s));
        }
    }
}

// ---------------- Kernel 2: modulated deformable conv ----------------
// Block = 512 threads = 8 waves; wave w handles deform-group g=w for the
// block's 64 pixels. Each thread accumulates ALL 64 output channels for its
// (pixel, g); gathers hit the channel-interleaved x0T (one cache line per
// bilinear corner). Cross-group reduction via LDS (pad-9, conflict-free).
__global__ void __launch_bounds__(512, 4)
deform_conv_kernel(const float* __restrict__ x0T,
                   const float* __restrict__ offset,
                   const float* __restrict__ mask,
                   const float* __restrict__ wT,
                   const float* __restrict__ bias,
                   float* __restrict__ out) {
    __shared__ float red[8 * 64 * 9];   // 18 KB

    int tid  = threadIdx.x;
    int lane = tid & 63;
    int g    = __builtin_amdgcn_readfirstlane(tid >> 6);  // wave-uniform
    int pbase = blockIdx.x * 64;
    int b     = blockIdx.y;
    int p = pbase + lane;
    int h = p >> 7;
    int w = p & (W - 1);

    float acc[O];
#pragma unroll
    for (int o = 0; o < O; ++o) acc[o] = 0.0f;

    const float* offb = offset + (size_t)b * OFF_C * HW + p;
    const float* mb   = mask + (size_t)b * MSK_C * HW + p;
    const float* xg   = x0T + ((size_t)(b * DG + g) * HW) * CG;

    for (int i = 0; i < KK; ++i) {
        int gi = g * KK + i;
        float offy = offb[(2 * gi) * HW];
        float offx = offb[(2 * gi + 1) * HW];
        float m    = mb[gi * HW];

        float py = offy + (float)(h - 1 + i / 3);
        float px = offx + (float)(w - 1 + i % 3);
        float fy = floorf(py), fx = floorf(px);
        float ly = py - fy, lx = px - fx;
        float hy = 1.0f - ly, hx = 1.0f - lx;
        int y0 = (int)fy, x0i = (int)fx;
        int y1 = y0 + 1, x1i = x0i + 1;
        bool vy0 = (y0 >= 0) && (y0 < H);
        bool vy1 = (y1 >= 0) && (y1 < H);
        bool vx0 = (x0i >= 0) && (x0i < W);
        bool vx1 = (x1i >= 0) && (x1i < W);
        int cy0 = min(max(y0, 0), H - 1), cy1 = min(max(y1, 0), H - 1);
        int cx0 = min(max(x0i, 0), W - 1), cx1 = min(max(x1i, 0), W - 1);
        float w00 = hy * hx * ((vy0 && vx0) ? 1.0f : 0.0f) * m;
        float w01 = hy * lx * ((vy0 && vx1) ? 1.0f : 0.0f) * m;
        float w10 = ly * hx * ((vy1 && vx0) ? 1.0f : 0.0f) * m;
        float w11 = ly * lx * ((vy1 && vx1) ? 1.0f : 0.0f) * m;
        int i00 = cy0 * W + cx0, i01 = cy0 * W + cx1;
        int i10 = cy1 * W + cx0, i11 = cy1 * W + cx1;

        const float4* A = (const float4*)(xg + (size_t)i00 * CG);
        const float4* Bc = (const float4*)(xg + (size_t)i01 * CG);
        const float4* Cc = (const float4*)(xg + (size_t)i10 * CG);
        const float4* Dc = (const float4*)(xg + (size_t)i11 * CG);
        float4 a0 = A[0],  a1 = A[1];
        float4 b0 = Bc[0], b1 = Bc[1];
        float4 c0 = Cc[0], c1 = Cc[1];
        float4 d0 = Dc[0], d1 = Dc[1];

        float v[CG];
        v[0] = w00 * a0.x + w01 * b0.x + w10 * c0.x + w11 * d0.x;
        v[1] = w00 * a0.y + w01 * b0.y + w10 * c0.y + w11 * d0.y;
        v[2] = w00 * a0.z + w01 * b0.z + w10 * c0.z + w11 * d0.z;
        v[3] = w00 * a0.w + w01 * b0.w + w10 * c0.w + w11 * d0.w;
        v[4] = w00 * a1.x + w01 * b1.x + w10 * c1.x + w11 * d1.x;
        v[5] = w00 * a1.y + w01 * b1.y + w10 * c1.y + w11 * d1.y;
        v[6] = w00 * a1.z + w01 * b1.z + w10 * c1.z + w11 * d1.z;
        v[7] = w00 * a1.w + w01 * b1.w + w10 * c1.w + w11 * d1.w;

        const float* wrow = wT + (size_t)(gi * CG) * O;   // wave-uniform
#pragma unroll
        for (int c = 0; c < CG; ++c) {
#pragma unroll
            for (int o = 0; o < O; ++o)
                acc[o] = fmaf(v[c], wrow[c * O + o], acc[o]);
        }
    }

    // Cross-group reduction: 8 chunks of 8 output channels.
    int ocp = tid >> 6;   // this thread's oc-within-chunk for the read phase
#pragma unroll
    for (int chunk = 0; chunk < 8; ++chunk) {
        float* slot = &red[(g * 64 + lane) * 9];
#pragma unroll
        for (int j = 0; j < 8; ++j) slot[j] = acc[chunk * 8 + j];
        __syncthreads();
        float s = 0.0f;
#pragma unroll
        for (int wv = 0; wv < 8; ++wv) s += red[(wv * 64 + lane) * 9 + ocp];
        int oc = chunk * 8 + ocp;
        out[((size_t)b * O + oc) * HW + pbase + lane] = s + bias[oc];
        __syncthreads();
    }
}

// ---------------- Launch ----------------
extern "C" void kernel_launch(void* const* d_in, const int* in_sizes, int n_in,
                              void* d_out, int out_size, void* d_ws, size_t ws_size,
                              hipStream_t stream) {
    (void)in_sizes; (void)n_in; (void)out_size; (void)ws_size;
    const float* x0         = (const float*)d_in[0];
    const float* x1         = (const float*)d_in[1];
    const float* pre_offset = (const float*)d_in[2];
    const float* pre_sim    = (const float*)d_in[3];
    const float* weight     = (const float*)d_in[4];
    const float* bias       = (const float*)d_in[5];
    const float* w_om       = (const float*)d_in[6];
    const float* b_om       = (const float*)d_in[7];
    float* out = (float*)d_out;

    // ws layout (floats):
    float* offset = (float*)d_ws;                       // B*144*HW
    float* mask   = offset + (size_t)B * OFF_C * HW;    // B*72*HW
    float* wT     = mask + (size_t)B * MSK_C * HW;      // 576*64
    float* w_omT  = wT + WT_N;                          // 576*216
    float* x0T    = w_omT + WOMT_N;                     // B*C*HW

    {
        int total = X0T_N + WT_N + WOMT_N;   // 2258432
        prep_kernel<<<(total + 255) / 256, 256, 0, stream>>>(
            weight, w_om, x0, wT, w_omT, x0T);
    }
    {
        dim3 grid(HW / 256, OM_C / OCPT1, B);   // (64, 9, 2)
        conv_offset_mask_kernel<<<grid, 256, 0, stream>>>(
            x1, w_omT, b_om, pre_offset, pre_sim, offset, mask);
    }
    {
        dim3 grid(HW / 64, B);                  // (256, 2) x 512 threads
        deform_conv_kernel<<<grid, 512, 0, stream>>>(
            x0T, offset, mask, wT, bias, out);
    }
}

// Round 4
// 125.919 us; speedup vs baseline: 16.8859x; 1.4050x over previous
//
#include <hip/hip_runtime.h>
#include <hip/hip_bf16.h>
#include <math.h>

// Problem constants
constexpr int B  = 2;
constexpr int C  = 64;
constexpr int H  = 128;
constexpr int W  = 128;
constexpr int O  = 64;
constexpr int DG = 8;
constexpr int K  = 3;
constexpr int KK = K * K;           // 9
constexpr int HW = H * W;           // 16384
constexpr int CG = C / DG;          // 8
constexpr int OM_C  = 3 * DG * KK;  // 216
constexpr int OFF_C = 2 * DG * KK;  // 144
constexpr int MSK_C = DG * KK;      // 72
constexpr float MRM = 10.0f;

typedef unsigned short u16;
typedef short bfx8 __attribute__((ext_vector_type(8)));   // 8 bf16 (4 VGPRs)
typedef float fx4 __attribute__((ext_vector_type(4)));    // MFMA accumulator

// Sizes
constexpr int WT_N   = 576 * 64;        // deform weights, transposed
constexpr int X0T_N  = B * C * HW;      // 2097152 floats (x0 interleaved)
constexpr int NFRAG  = 14;              // 224 padded output channels / 16
constexpr int SLAB_E = NFRAG * 64 * 8;  // 7168 bf16 per (tap,wsel,chunk) slab
constexpr int WB_N   = 9 * 2 * 2 * SLAB_E;  // 258048

// ---------------- prep1: wT (deform), x1T hi/lo (pixel-major bf16), wB ----
__global__ void __launch_bounds__(256)
prep1_kernel(const float* __restrict__ weight,
             const float* __restrict__ w_om,
             const float* __restrict__ x1,
             float* __restrict__ wT,
             u16* __restrict__ x1T_hi,
             u16* __restrict__ x1T_lo,
             u16* __restrict__ wB) {
    int idx = blockIdx.x * 256 + threadIdx.x;
    if (idx < WT_N) {
        int r = idx / O;          // (g*KK+i)*CG + c
        int o = idx - r * O;
        int g = r / (KK * CG);
        int rem = r - g * (KK * CG);
        int i = rem / CG;
        int c = rem - i * CG;
        wT[idx] = weight[o * (C * KK) + (g * CG + c) * KK + i];
        return;
    }
    int i1 = idx - WT_N;
    if (i1 < B * HW) {   // one thread per (b,p): transpose x1 to [b][p][ic] bf16 hi/lo
        int p = i1 & (HW - 1);
        int b = i1 >> 14;
        const float* xp = x1 + (size_t)b * C * HW + p;
        bfx8 vh[8], vl[8];
#pragma unroll
        for (int k = 0; k < 8; ++k) {
#pragma unroll
            for (int j = 0; j < 8; ++j) {
                float x = xp[(size_t)(k * 8 + j) * HW];
                __hip_bfloat16 hb = __float2bfloat16(x);
                float hf = __bfloat162float(hb);
                __hip_bfloat16 lb = __float2bfloat16(x - hf);
                vh[k][j] = *(short*)&hb;
                vl[k][j] = *(short*)&lb;
            }
        }
        u16* dh = x1T_hi + (size_t)i1 * C;
        u16* dl = x1T_lo + (size_t)i1 * C;
#pragma unroll
        for (int k = 0; k < 8; ++k) {
            *(bfx8*)(dh + k * 8) = vh[k];
            *(bfx8*)(dl + k * 8) = vl[k];
        }
        return;
    }
    int i2 = i1 - B * HW;
    if (i2 < WB_N) {   // B-fragment-ordered conv_offset weights, hi & lo
        int slab = i2 / SLAB_E;
        int within = i2 - slab * SLAB_E;
        int nf   = within >> 9;          // 0..13
        int lane = (within >> 3) & 63;
        int j    = within & 7;
        int t    = slab >> 2;            // tap 0..8
        int wsel = (slab >> 1) & 1;      // 0=hi, 1=lo
        int chunk = slab & 1;            // ic chunk of 32
        int ic = chunk * 32 + ((lane >> 4) << 3) + j;
        int oc = (nf << 4) + (lane & 15);
        float v = (oc < OM_C) ? w_om[oc * (C * KK) + ic * KK + t] : 0.0f;
        __hip_bfloat16 hb = __float2bfloat16(v);
        if (wsel == 0) {
            wB[i2] = *(u16*)&hb;
        } else {
            float hf = __bfloat162float(hb);
            __hip_bfloat16 lb = __float2bfloat16(v - hf);
            wB[i2] = *(u16*)&lb;
        }
    }
}

// ---------------- prep2: x0 channel-interleave (after conv frees the union) --
__global__ void __launch_bounds__(256)
prep2_kernel(const float* __restrict__ x0, float* __restrict__ x0T) {
    int idx = blockIdx.x * 256 + threadIdx.x;
    int p  = idx & (HW - 1);
    int ch = (idx >> 14) & (C - 1);
    int b  = idx >> 20;
    x0T[((size_t)((b * DG + (ch >> 3)) * HW + p) << 3) + (ch & 7)] = x0[idx];
}

// ---------------- conv_offset_mask via split-precision MFMA ----------------
// Block = 256 thr = 4 waves (2 pixel-rows x 2 oc-cols). Wave tile: M=32 px,
// N=112 oc (7 frags). K = 9 taps x 64 ic x {xh*wh, xl*wh, xh*wl}.
__global__ void __launch_bounds__(256)
conv_om_mfma_kernel(const u16* __restrict__ x1T_hi,
                    const u16* __restrict__ x1T_lo,
                    const u16* __restrict__ wB,
                    const float* __restrict__ b_om,
                    const float* __restrict__ pre_offset,
                    const float* __restrict__ pre_sim,
                    float* __restrict__ offset,
                    float* __restrict__ mask) {
    __shared__ float lds[224 * 68];   // [oc][pix], pix-dim padded 64->68

    int tid  = threadIdx.x;
    int lane = tid & 63;
    int wid  = tid >> 6;
    int wrow = wid >> 1;      // pixel half
    int wcol = wid & 1;       // oc half
    int px0  = blockIdx.x * 64;
    int b    = blockIdx.y;

    fx4 acc[2][7];
#pragma unroll
    for (int mf = 0; mf < 2; ++mf)
#pragma unroll
        for (int nf = 0; nf < 7; ++nf) acc[mf][nf] = fx4{0.f, 0.f, 0.f, 0.f};

    int prow  = px0 + wrow * 32 + (lane & 15);   // + mf*16
    int klane = (lane >> 4) << 3;

    const u16* xh_b = x1T_hi + (size_t)b * HW * C;
    const u16* xl_b = x1T_lo + (size_t)b * HW * C;

    for (int t = 0; t < KK; ++t) {
        int dy = t / 3 - 1, dx = t % 3 - 1;
        int  pp[2];
        bool vv[2];
#pragma unroll
        for (int mf = 0; mf < 2; ++mf) {
            int p = prow + mf * 16;
            int hh = (p >> 7) + dy;
            int ww = (p & (W - 1)) + dx;
            vv[mf] = ((unsigned)hh < (unsigned)H) && ((unsigned)ww < (unsigned)W);
            pp[mf] = (hh << 7) + ww;
        }
        const u16* slab_h = wB + (size_t)((t * 2 + 0) * 2) * SLAB_E;  // +chunk*SLAB_E
        const u16* slab_l = wB + (size_t)((t * 2 + 1) * 2) * SLAB_E;
#pragma unroll
        for (int chunk = 0; chunk < 2; ++chunk) {
            bfx8 ah[2], al[2];
#pragma unroll
            for (int mf = 0; mf < 2; ++mf) {
                bfx8 zh = {0, 0, 0, 0, 0, 0, 0, 0};
                bfx8 zl = {0, 0, 0, 0, 0, 0, 0, 0};
                if (vv[mf]) {
                    size_t off = (size_t)pp[mf] * C + chunk * 32 + klane;
                    zh = *(const bfx8*)(xh_b + off);
                    zl = *(const bfx8*)(xl_b + off);
                }
                ah[mf] = zh;
                al[mf] = zl;
            }
#pragma unroll
            for (int nf = 0; nf < 7; ++nf) {
                int boff = chunk * SLAB_E + ((wcol * 7 + nf) << 9) + (lane << 3);
                bfx8 bh = *(const bfx8*)(slab_h + boff);
                bfx8 bl = *(const bfx8*)(slab_l + boff);
#pragma unroll
                for (int mf = 0; mf < 2; ++mf) {
                    acc[mf][nf] = __builtin_amdgcn_mfma_f32_16x16x32_bf16(ah[mf], bh, acc[mf][nf], 0, 0, 0);
                    acc[mf][nf] = __builtin_amdgcn_mfma_f32_16x16x32_bf16(al[mf], bh, acc[mf][nf], 0, 0, 0);
                    acc[mf][nf] = __builtin_amdgcn_mfma_f32_16x16x32_bf16(ah[mf], bl, acc[mf][nf], 0, 0, 0);
                }
            }
        }
    }

    // acc -> LDS transpose. D frag: col(oc) = lane&15, row(pix) = (lane>>4)*4+r.
#pragma unroll
    for (int mf = 0; mf < 2; ++mf)
#pragma unroll
        for (int nf = 0; nf < 7; ++nf) {
            int oc  = wcol * 112 + nf * 16 + (lane & 15);
            int pix = wrow * 32 + mf * 16 + ((lane >> 4) << 2);
            *(fx4*)&lds[oc * 68 + pix] = acc[mf][nf];
        }
    __syncthreads();

    // Epilogue: coalesced float4 streams.
    int c4    = (tid & 15) * 4;
    int rbase = tid >> 4;
#pragma unroll
    for (int pass = 0; pass < 14; ++pass) {
        int row = pass * 16 + rbase;
        if (row >= OM_C) continue;
        float4 v = *(float4*)&lds[row * 68 + c4];
        float bb = b_om[row];
        v.x += bb; v.y += bb; v.z += bb; v.w += bb;
        int gp = px0 + c4;
        if (row < OFF_C) {
            size_t oi = (size_t)(b * OFF_C + row) * HW + gp;
            float4 po = *(const float4*)&pre_offset[oi];
            float4 r;
            r.x = MRM * tanhf(v.x) + po.x;
            r.y = MRM * tanhf(v.y) + po.y;
            r.z = MRM * tanhf(v.z) + po.z;
            r.w = MRM * tanhf(v.w) + po.w;
            *(float4*)&offset[oi] = r;
        } else {
            int mr = row - OFF_C;
            size_t mi = (size_t)(b * MSK_C + mr) * HW + gp;
            float4 ps = *(const float4*)&pre_sim[mi];
            float4 r;
            r.x = 1.0f / (1.0f + expf(-v.x * ps.x));
            r.y = 1.0f / (1.0f + expf(-v.y * ps.y));
            r.z = 1.0f / (1.0f + expf(-v.z * ps.z));
            r.w = 1.0f / (1.0f + expf(-v.w * ps.w));
            *(float4*)&mask[mi] = r;
        }
    }
}

// ---------------- Kernel: modulated deformable conv (round-3 design) -------
__global__ void __launch_bounds__(512, 4)
deform_conv_kernel(const float* __restrict__ x0T,
                   const float* __restrict__ offset,
                   const float* __restrict__ mask,
                   const float* __restrict__ wT,
                   const float* __restrict__ bias,
                   float* __restrict__ out) {
    __shared__ float red[8 * 64 * 9];   // 18 KB

    int tid  = threadIdx.x;
    int lane = tid & 63;
    int g    = __builtin_amdgcn_readfirstlane(tid >> 6);  // wave-uniform
    int pbase = blockIdx.x * 64;
    int b     = blockIdx.y;
    int p = pbase + lane;
    int h = p >> 7;
    int w = p & (W - 1);

    float acc[O];
#pragma unroll
    for (int o = 0; o < O; ++o) acc[o] = 0.0f;

    const float* offb = offset + (size_t)b * OFF_C * HW + p;
    const float* mb   = mask + (size_t)b * MSK_C * HW + p;
    const float* xg   = x0T + ((size_t)(b * DG + g) * HW) * CG;

    for (int i = 0; i < KK; ++i) {
        int gi = g * KK + i;
        float offy = offb[(2 * gi) * HW];
        float offx = offb[(2 * gi + 1) * HW];
        float m    = mb[gi * HW];

        float py = offy + (float)(h - 1 + i / 3);
        float px = offx + (float)(w - 1 + i % 3);
        float fy = floorf(py), fx = floorf(px);
        float ly = py - fy, lx = px - fx;
        float hy = 1.0f - ly, hx = 1.0f - lx;
        int y0 = (int)fy, x0i = (int)fx;
        int y1 = y0 + 1, x1i = x0i + 1;
        bool vy0 = (y0 >= 0) && (y0 < H);
        bool vy1 = (y1 >= 0) && (y1 < H);
        bool vx0 = (x0i >= 0) && (x0i < W);
        bool vx1 = (x1i >= 0) && (x1i < W);
        int cy0 = min(max(y0, 0), H - 1), cy1 = min(max(y1, 0), H - 1);
        int cx0 = min(max(x0i, 0), W - 1), cx1 = min(max(x1i, 0), W - 1);
        float w00 = hy * hx * ((vy0 && vx0) ? 1.0f : 0.0f) * m;
        float w01 = hy * lx * ((vy0 && vx1) ? 1.0f : 0.0f) * m;
        float w10 = ly * hx * ((vy1 && vx0) ? 1.0f : 0.0f) * m;
        float w11 = ly * lx * ((vy1 && vx1) ? 1.0f : 0.0f) * m;
        int i00 = cy0 * W + cx0, i01 = cy0 * W + cx1;
        int i10 = cy1 * W + cx0, i11 = cy1 * W + cx1;

        const float4* A  = (const float4*)(xg + (size_t)i00 * CG);
        const float4* Bc = (const float4*)(xg + (size_t)i01 * CG);
        const float4* Cc = (const float4*)(xg + (size_t)i10 * CG);
        const float4* Dc = (const float4*)(xg + (size_t)i11 * CG);
        float4 a0 = A[0],  a1 = A[1];
        float4 b0 = Bc[0], b1 = Bc[1];
        float4 c0 = Cc[0], c1 = Cc[1];
        float4 d0 = Dc[0], d1 = Dc[1];

        float v[CG];
        v[0] = w00 * a0.x + w01 * b0.x + w10 * c0.x + w11 * d0.x;
        v[1] = w00 * a0.y + w01 * b0.y + w10 * c0.y + w11 * d0.y;
        v[2] = w00 * a0.z + w01 * b0.z + w10 * c0.z + w11 * d0.z;
        v[3] = w00 * a0.w + w01 * b0.w + w10 * c0.w + w11 * d0.w;
        v[4] = w00 * a1.x + w01 * b1.x + w10 * c1.x + w11 * d1.x;
        v[5] = w00 * a1.y + w01 * b1.y + w10 * c1.y + w11 * d1.y;
        v[6] = w00 * a1.z + w01 * b1.z + w10 * c1.z + w11 * d1.z;
        v[7] = w00 * a1.w + w01 * b1.w + w10 * c1.w + w11 * d1.w;

        const float* wrow = wT + (size_t)(gi * CG) * O;   // wave-uniform
#pragma unroll
        for (int c = 0; c < CG; ++c) {
#pragma unroll
            for (int o = 0; o < O; ++o)
                acc[o] = fmaf(v[c], wrow[c * O + o], acc[o]);
        }
    }

    // Cross-group reduction: 8 chunks of 8 output channels.
    int ocp = tid >> 6;
#pragma unroll
    for (int chunk = 0; chunk < 8; ++chunk) {
        float* slot = &red[(g * 64 + lane) * 9];
#pragma unroll
        for (int j = 0; j < 8; ++j) slot[j] = acc[chunk * 8 + j];
        __syncthreads();
        float s = 0.0f;
#pragma unroll
        for (int wv = 0; wv < 8; ++wv) s += red[(wv * 64 + lane) * 9 + ocp];
        int oc = chunk * 8 + ocp;
        out[((size_t)b * O + oc) * HW + pbase + lane] = s + bias[oc];
        __syncthreads();
    }
}

// ---------------- Launch ----------------
extern "C" void kernel_launch(void* const* d_in, const int* in_sizes, int n_in,
                              void* d_out, int out_size, void* d_ws, size_t ws_size,
                              hipStream_t stream) {
    (void)in_sizes; (void)n_in; (void)out_size; (void)ws_size;
    const float* x0         = (const float*)d_in[0];
    const float* x1         = (const float*)d_in[1];
    const float* pre_offset = (const float*)d_in[2];
    const float* pre_sim    = (const float*)d_in[3];
    const float* weight     = (const float*)d_in[4];
    const float* bias       = (const float*)d_in[5];
    const float* w_om       = (const float*)d_in[6];
    const float* b_om       = (const float*)d_in[7];
    float* out = (float*)d_out;

    // ws layout (floats):
    float* offset = (float*)d_ws;                       // B*144*HW
    float* mask   = offset + (size_t)B * OFF_C * HW;    // B*72*HW
    float* wT     = mask + (size_t)B * MSK_C * HW;      // 36864
    float* xbuf   = wT + WT_N;                          // union region (2097152 floats)
    u16*   x1T_hi = (u16*)xbuf;                         // B*HW*C bf16
    u16*   x1T_lo = x1T_hi + (size_t)B * HW * C;        // B*HW*C bf16
    float* x0T    = xbuf;                               // reuses x1T region (after conv)
    u16*   wB     = (u16*)(xbuf + X0T_N);               // 258048 bf16

    {
        int total = WT_N + B * HW + WB_N;   // 327680
        prep1_kernel<<<total / 256, 256, 0, stream>>>(
            weight, w_om, x1, wT, x1T_hi, x1T_lo, wB);
    }
    {
        dim3 grid(HW / 64, B);              // (256, 2)
        conv_om_mfma_kernel<<<grid, 256, 0, stream>>>(
            x1T_hi, x1T_lo, wB, b_om, pre_offset, pre_sim, offset, mask);
    }
    {
        prep2_kernel<<<X0T_N / 256, 256, 0, stream>>>(x0, x0T);
    }
    {
        dim3 grid(HW / 64, B);              // (256, 2) x 512 threads
        deform_conv_kernel<<<grid, 512, 0, stream>>>(
            x0T, offset, mask, wT, bias, out);
    }
}

// Round 5
// 119.184 us; speedup vs baseline: 17.8402x; 1.0565x over previous
//
#include <hip/hip_runtime.h>
#include <hip/hip_bf16.h>
#include <math.h>

// Problem constants
constexpr int B  = 2;
constexpr int C  = 64;
constexpr int H  = 128;
constexpr int W  = 128;
constexpr int O  = 64;
constexpr int DG = 8;
constexpr int K  = 3;
constexpr int KK = K * K;           // 9
constexpr int HW = H * W;           // 16384
constexpr int CG = C / DG;          // 8
constexpr int OM_C  = 3 * DG * KK;  // 216
constexpr int OFF_C = 2 * DG * KK;  // 144
constexpr int MSK_C = DG * KK;      // 72
constexpr float MRM = 10.0f;

typedef unsigned short u16;
typedef short bfx8 __attribute__((ext_vector_type(8)));   // 8 bf16 (4 VGPRs)
typedef float fx4 __attribute__((ext_vector_type(4)));    // MFMA accumulator

// Sizes
constexpr int WT_N   = 576 * 64;        // deform weights, transposed
constexpr int X0T_N  = B * C * HW;      // 2097152 floats (x0 interleaved)
constexpr int NFRAG  = 14;              // 224 padded output channels / 16
constexpr int SLAB_E = NFRAG * 64 * 8;  // 7168 bf16 per (tap,wsel,chunk) slab
constexpr int WB_N   = 9 * 2 * 2 * SLAB_E;  // 258048

// ---------------- prep1: wT (deform), x1T hi/lo (pixel-major bf16), wB ----
__global__ void __launch_bounds__(256)
prep1_kernel(const float* __restrict__ weight,
             const float* __restrict__ w_om,
             const float* __restrict__ x1,
             float* __restrict__ wT,
             u16* __restrict__ x1T_hi,
             u16* __restrict__ x1T_lo,
             u16* __restrict__ wB) {
    int idx = blockIdx.x * 256 + threadIdx.x;
    if (idx < WT_N) {
        int r = idx / O;          // (g*KK+i)*CG + c
        int o = idx - r * O;
        int g = r / (KK * CG);
        int rem = r - g * (KK * CG);
        int i = rem / CG;
        int c = rem - i * CG;
        wT[idx] = weight[o * (C * KK) + (g * CG + c) * KK + i];
        return;
    }
    int i1 = idx - WT_N;
    if (i1 < B * HW) {   // one thread per (b,p): transpose x1 to [b][p][ic] bf16 hi/lo
        int p = i1 & (HW - 1);
        int b = i1 >> 14;
        const float* xp = x1 + (size_t)b * C * HW + p;
        bfx8 vh[8], vl[8];
#pragma unroll
        for (int k = 0; k < 8; ++k) {
#pragma unroll
            for (int j = 0; j < 8; ++j) {
                float x = xp[(size_t)(k * 8 + j) * HW];
                __hip_bfloat16 hb = __float2bfloat16(x);
                float hf = __bfloat162float(hb);
                __hip_bfloat16 lb = __float2bfloat16(x - hf);
                vh[k][j] = *(short*)&hb;
                vl[k][j] = *(short*)&lb;
            }
        }
        u16* dh = x1T_hi + (size_t)i1 * C;
        u16* dl = x1T_lo + (size_t)i1 * C;
#pragma unroll
        for (int k = 0; k < 8; ++k) {
            *(bfx8*)(dh + k * 8) = vh[k];
            *(bfx8*)(dl + k * 8) = vl[k];
        }
        return;
    }
    int i2 = i1 - B * HW;
    if (i2 < WB_N) {   // B-fragment-ordered conv_offset weights, hi & lo
        int slab = i2 / SLAB_E;
        int within = i2 - slab * SLAB_E;
        int nf   = within >> 9;          // 0..13
        int lane = (within >> 3) & 63;
        int j    = within & 7;
        int t    = slab >> 2;            // tap 0..8
        int wsel = (slab >> 1) & 1;      // 0=hi, 1=lo
        int chunk = slab & 1;            // ic chunk of 32
        int ic = chunk * 32 + ((lane >> 4) << 3) + j;
        int oc = (nf << 4) + (lane & 15);
        float v = (oc < OM_C) ? w_om[oc * (C * KK) + ic * KK + t] : 0.0f;
        __hip_bfloat16 hb = __float2bfloat16(v);
        if (wsel == 0) {
            wB[i2] = *(u16*)&hb;
        } else {
            float hf = __bfloat162float(hb);
            __hip_bfloat16 lb = __float2bfloat16(v - hf);
            wB[i2] = *(u16*)&lb;
        }
    }
}

// ---------------- prep2: x0 channel-interleave (after conv frees the union) --
__global__ void __launch_bounds__(256)
prep2_kernel(const float* __restrict__ x0, float* __restrict__ x0T) {
    int idx = blockIdx.x * 256 + threadIdx.x;
    int p  = idx & (HW - 1);
    int ch = (idx >> 14) & (C - 1);
    int b  = idx >> 20;
    x0T[((size_t)((b * DG + (ch >> 3)) * HW + p) << 3) + (ch & 7)] = x0[idx];
}

// ---------------- conv_offset_mask via split-precision MFMA, K-split x2 ----
// Block = 512 thr = 8 waves = 2 wrow x 2 wcol x 2 kid. Wave tile: M=32 px,
// N=112 oc. K-steps (tap x ic-chunk, 18 total) split across the kid pair:
// kid0 -> tc 0..8, kid1 -> tc 9..17. kid1 partials reduced via LDS; kid0
// stores directly from fragment layout (no transpose LDS).
__global__ void __launch_bounds__(512, 4)
conv_om_mfma_kernel(const u16* __restrict__ x1T_hi,
                    const u16* __restrict__ x1T_lo,
                    const u16* __restrict__ wB,
                    const float* __restrict__ b_om,
                    const float* __restrict__ pre_offset,
                    const float* __restrict__ pre_sim,
                    float* __restrict__ offset,
                    float* __restrict__ mask) {
    __shared__ fx4 red[4][14][64];   // 56 KB

    int tid  = threadIdx.x;
    int lane = tid & 63;
    int wid  = tid >> 6;
    int kid  = wid & 1;
    int wcol = (wid >> 1) & 1;
    int wrow = wid >> 2;
    int px0  = blockIdx.x * 64;
    int b    = blockIdx.y;

    fx4 acc[2][7];
#pragma unroll
    for (int mf = 0; mf < 2; ++mf)
#pragma unroll
        for (int nf = 0; nf < 7; ++nf) acc[mf][nf] = fx4{0.f, 0.f, 0.f, 0.f};

    int prow  = px0 + wrow * 32 + (lane & 15);   // + mf*16
    int klane = (lane >> 4) << 3;

    const u16* xh_b = x1T_hi + (size_t)b * HW * C;
    const u16* xl_b = x1T_lo + (size_t)b * HW * C;

#pragma unroll
    for (int j = 0; j < 9; ++j) {
        int tc = kid * 9 + j;       // 0..17
        int t = tc >> 1;
        int chunk = tc & 1;
        int ty = t / 3;
        int dy = ty - 1, dx = (t - ty * 3) - 1;

        int  pp[2];
        bool vv[2];
#pragma unroll
        for (int mf = 0; mf < 2; ++mf) {
            int p = prow + mf * 16;
            int hh = (p >> 7) + dy;
            int ww = (p & (W - 1)) + dx;
            vv[mf] = ((unsigned)hh < (unsigned)H) && ((unsigned)ww < (unsigned)W);
            pp[mf] = (hh << 7) + ww;
        }

        const u16* slab_h = wB + (size_t)(t * 4 + chunk) * SLAB_E;
        const u16* slab_l = wB + (size_t)(t * 4 + 2 + chunk) * SLAB_E;

        bfx8 ah[2], al[2];
#pragma unroll
        for (int mf = 0; mf < 2; ++mf) {
            bfx8 zh = {0, 0, 0, 0, 0, 0, 0, 0};
            bfx8 zl = {0, 0, 0, 0, 0, 0, 0, 0};
            if (vv[mf]) {
                size_t off = (size_t)pp[mf] * C + chunk * 32 + klane;
                zh = *(const bfx8*)(xh_b + off);
                zl = *(const bfx8*)(xl_b + off);
            }
            ah[mf] = zh;
            al[mf] = zl;
        }
#pragma unroll
        for (int nf = 0; nf < 7; ++nf) {
            int boff = ((wcol * 7 + nf) << 9) + (lane << 3);
            bfx8 bh = *(const bfx8*)(slab_h + boff);
            bfx8 bl = *(const bfx8*)(slab_l + boff);
#pragma unroll
            for (int mf = 0; mf < 2; ++mf) {
                acc[mf][nf] = __builtin_amdgcn_mfma_f32_16x16x32_bf16(ah[mf], bh, acc[mf][nf], 0, 0, 0);
                acc[mf][nf] = __builtin_amdgcn_mfma_f32_16x16x32_bf16(al[mf], bh, acc[mf][nf], 0, 0, 0);
                acc[mf][nf] = __builtin_amdgcn_mfma_f32_16x16x32_bf16(ah[mf], bl, acc[mf][nf], 0, 0, 0);
            }
        }
    }

    int slot = wrow * 2 + wcol;
    if (kid) {
#pragma unroll
        for (int mf = 0; mf < 2; ++mf)
#pragma unroll
            for (int nf = 0; nf < 7; ++nf)
                red[slot][mf * 7 + nf][lane] = acc[mf][nf];
    }
    __syncthreads();
    if (!kid) {
        // Epilogue from fragment layout: col(oc)=lane&15, row(pix)=(lane>>4)*4+r.
#pragma unroll
        for (int mf = 0; mf < 2; ++mf) {
#pragma unroll
            for (int nf = 0; nf < 7; ++nf) {
                fx4 v = acc[mf][nf] + red[slot][mf * 7 + nf][lane];
                int oc  = wcol * 112 + nf * 16 + (lane & 15);
                int pix = px0 + wrow * 32 + mf * 16 + ((lane >> 4) << 2);
                if (oc < OM_C) {
                    float bb = b_om[oc];
                    if (oc < OFF_C) {
                        size_t oi = (size_t)(b * OFF_C + oc) * HW + pix;
                        float4 po = *(const float4*)&pre_offset[oi];
                        float4 r;
                        r.x = MRM * tanhf(v[0] + bb) + po.x;
                        r.y = MRM * tanhf(v[1] + bb) + po.y;
                        r.z = MRM * tanhf(v[2] + bb) + po.z;
                        r.w = MRM * tanhf(v[3] + bb) + po.w;
                        *(float4*)&offset[oi] = r;
                    } else {
                        size_t mi = (size_t)(b * MSK_C + oc - OFF_C) * HW + pix;
                        float4 ps = *(const float4*)&pre_sim[mi];
                        float4 r;
                        r.x = 1.0f / (1.0f + expf(-(v[0] + bb) * ps.x));
                        r.y = 1.0f / (1.0f + expf(-(v[1] + bb) * ps.y));
                        r.z = 1.0f / (1.0f + expf(-(v[2] + bb) * ps.z));
                        r.w = 1.0f / (1.0f + expf(-(v[3] + bb) * ps.w));
                        *(float4*)&mask[mi] = r;
                    }
                }
            }
        }
    }
}

// ---------------- Kernel: modulated deformable conv -----------------------
__global__ void __launch_bounds__(512, 4)
deform_conv_kernel(const float* __restrict__ x0T,
                   const float* __restrict__ offset,
                   const float* __restrict__ mask,
                   const float* __restrict__ wT,
                   const float* __restrict__ bias,
                   float* __restrict__ out) {
    __shared__ float red[8 * 64 * 9];   // 18 KB

    int tid  = threadIdx.x;
    int lane = tid & 63;
    int g    = __builtin_amdgcn_readfirstlane(tid >> 6);  // wave-uniform
    int pbase = blockIdx.x * 64;
    int b     = blockIdx.y;
    int p = pbase + lane;
    int h = p >> 7;
    int w = p & (W - 1);

    float acc[O];
#pragma unroll
    for (int o = 0; o < O; ++o) acc[o] = 0.0f;

    const float* offb = offset + (size_t)b * OFF_C * HW + p;
    const float* mb   = mask + (size_t)b * MSK_C * HW + p;
    const float* xg   = x0T + ((size_t)(b * DG + g) * HW) * CG;

    for (int i = 0; i < KK; ++i) {
        int gi = g * KK + i;
        float offy = offb[(2 * gi) * HW];
        float offx = offb[(2 * gi + 1) * HW];
        float m    = mb[gi * HW];

        float py = offy + (float)(h - 1 + i / 3);
        float px = offx + (float)(w - 1 + i % 3);
        float fy = floorf(py), fx = floorf(px);
        float ly = py - fy, lx = px - fx;
        float hy = 1.0f - ly, hx = 1.0f - lx;
        int y0 = (int)fy, x0i = (int)fx;
        int y1 = y0 + 1, x1i = x0i + 1;
        bool vy0 = (y0 >= 0) && (y0 < H);
        bool vy1 = (y1 >= 0) && (y1 < H);
        bool vx0 = (x0i >= 0) && (x0i < W);
        bool vx1 = (x1i >= 0) && (x1i < W);
        int cy0 = min(max(y0, 0), H - 1), cy1 = min(max(y1, 0), H - 1);
        int cx0 = min(max(x0i, 0), W - 1), cx1 = min(max(x1i, 0), W - 1);
        float w00 = hy * hx * ((vy0 && vx0) ? 1.0f : 0.0f) * m;
        float w01 = hy * lx * ((vy0 && vx1) ? 1.0f : 0.0f) * m;
        float w10 = ly * hx * ((vy1 && vx0) ? 1.0f : 0.0f) * m;
        float w11 = ly * lx * ((vy1 && vx1) ? 1.0f : 0.0f) * m;
        int i00 = cy0 * W + cx0, i01 = cy0 * W + cx1;
        int i10 = cy1 * W + cx0, i11 = cy1 * W + cx1;

        const float4* A  = (const float4*)(xg + (size_t)i00 * CG);
        const float4* Bc = (const float4*)(xg + (size_t)i01 * CG);
        const float4* Cc = (const float4*)(xg + (size_t)i10 * CG);
        const float4* Dc = (const float4*)(xg + (size_t)i11 * CG);
        float4 a0 = A[0],  a1 = A[1];
        float4 b0 = Bc[0], b1 = Bc[1];
        float4 c0 = Cc[0], c1 = Cc[1];
        float4 d0 = Dc[0], d1 = Dc[1];

        float v[CG];
        v[0] = w00 * a0.x + w01 * b0.x + w10 * c0.x + w11 * d0.x;
        v[1] = w00 * a0.y + w01 * b0.y + w10 * c0.y + w11 * d0.y;
        v[2] = w00 * a0.z + w01 * b0.z + w10 * c0.z + w11 * d0.z;
        v[3] = w00 * a0.w + w01 * b0.w + w10 * c0.w + w11 * d0.w;
        v[4] = w00 * a1.x + w01 * b1.x + w10 * c1.x + w11 * d1.x;
        v[5] = w00 * a1.y + w01 * b1.y + w10 * c1.y + w11 * d1.y;
        v[6] = w00 * a1.z + w01 * b1.z + w10 * c1.z + w11 * d1.z;
        v[7] = w00 * a1.w + w01 * b1.w + w10 * c1.w + w11 * d1.w;

        const float* wrow = wT + (size_t)(gi * CG) * O;   // wave-uniform
#pragma unroll
        for (int c = 0; c < CG; ++c) {
#pragma unroll
            for (int o = 0; o < O; ++o)
                acc[o] = fmaf(v[c], wrow[c * O + o], acc[o]);
        }
    }

    // Cross-group reduction: 8 chunks of 8 output channels.
    int ocp = tid >> 6;
#pragma unroll
    for (int chunk = 0; chunk < 8; ++chunk) {
        float* slot = &red[(g * 64 + lane) * 9];
#pragma unroll
        for (int j = 0; j < 8; ++j) slot[j] = acc[chunk * 8 + j];
        __syncthreads();
        float s = 0.0f;
#pragma unroll
        for (int wv = 0; wv < 8; ++wv) s += red[(wv * 64 + lane) * 9 + ocp];
        int oc = chunk * 8 + ocp;
        out[((size_t)b * O + oc) * HW + pbase + lane] = s + bias[oc];
        __syncthreads();
    }
}

// ---------------- Launch ----------------
extern "C" void kernel_launch(void* const* d_in, const int* in_sizes, int n_in,
                              void* d_out, int out_size, void* d_ws, size_t ws_size,
                              hipStream_t stream) {
    (void)in_sizes; (void)n_in; (void)out_size; (void)ws_size;
    const float* x0         = (const float*)d_in[0];
    const float* x1         = (const float*)d_in[1];
    const float* pre_offset = (const float*)d_in[2];
    const float* pre_sim    = (const float*)d_in[3];
    const float* weight     = (const float*)d_in[4];
    const float* bias       = (const float*)d_in[5];
    const float* w_om       = (const float*)d_in[6];
    const float* b_om       = (const float*)d_in[7];
    float* out = (float*)d_out;

    // ws layout (floats):
    float* offset = (float*)d_ws;                       // B*144*HW
    float* mask   = offset + (size_t)B * OFF_C * HW;    // B*72*HW
    float* wT     = mask + (size_t)B * MSK_C * HW;      // 36864
    float* xbuf   = wT + WT_N;                          // union region (2097152 floats)
    u16*   x1T_hi = (u16*)xbuf;                         // B*HW*C bf16
    u16*   x1T_lo = x1T_hi + (size_t)B * HW * C;        // B*HW*C bf16
    float* x0T    = xbuf;                               // reuses x1T region (after conv)
    u16*   wB     = (u16*)(xbuf + X0T_N);               // 258048 bf16

    {
        int total = WT_N + B * HW + WB_N;   // 327680
        prep1_kernel<<<total / 256, 256, 0, stream>>>(
            weight, w_om, x1, wT, x1T_hi, x1T_lo, wB);
    }
    {
        dim3 grid(HW / 64, B);              // (256, 2) x 512 threads
        conv_om_mfma_kernel<<<grid, 512, 0, stream>>>(
            x1T_hi, x1T_lo, wB, b_om, pre_offset, pre_sim, offset, mask);
    }
    {
        prep2_kernel<<<X0T_N / 256, 256, 0, stream>>>(x0, x0T);
    }
    {
        dim3 grid(HW / 64, B);              // (256, 2) x 512 threads
        deform_conv_kernel<<<grid, 512, 0, stream>>>(
            x0T, offset, mask, wT, bias, out);
    }
}